// Round 2
// baseline (1209.755 us; speedup 1.0000x reference)
//
#include <hip/hip_runtime.h>

#define F_IN 512
#define HDIM 16
#define F_OUT 40
#define BTGT 64          // targets per bucket
#define REPL 4           // contention-splitting replicas per bucket

__device__ __forceinline__ int load_idx(const void* ei, int is64, long long i) {
  if (is64) return (int)((const long long*)ei)[i];
  return ((const int*)ei)[i];
}

extern "C" __global__ void k_init(int* __restrict__ cnt, int n, int* __restrict__ hist, int m,
                                  int* __restrict__ flag) {
  int i = blockIdx.x * blockDim.x + threadIdx.x;
  if (i < n) cnt[i] = 0;
  if (i < m) hist[i] = 0;
  if (i == 0) *flag = 1;
}

// int64 edge_index => all high halves of first npairs values are zero.
extern "C" __global__ void k_detect(const unsigned int* __restrict__ w, int npairs,
                                    int* __restrict__ flag) {
  int i = blockIdx.x * blockDim.x + threadIdx.x;
  if (i < npairs && w[2 * i + 1] != 0u) atomicAnd(flag, 0);
}

// degree count + bucket histogram (REPL-split by blockIdx to cut contention)
extern "C" __global__ void k_hist(const void* __restrict__ ei, int E, int* __restrict__ cnt,
                                  int* __restrict__ hist, const int* __restrict__ flag) {
  int e = blockIdx.x * blockDim.x + threadIdx.x;
  if (e >= E) return;
  int is64 = *flag;
  int c = load_idx(ei, is64, (long long)E + e);
  atomicAdd(&cnt[c], 1);
  int idx = (c >> 6) * REPL + (blockIdx.x & (REPL - 1));
  atomicAdd(&hist[idx], 1);
}

extern "C" __global__ void k_dis(const int* __restrict__ cnt, float* __restrict__ dis, int n) {
  int i = blockIdx.x * blockDim.x + threadIdx.x;
  if (i < n) dis[i] = rsqrtf((float)cnt[i] + 1.0f);  // +1 self loop
}

// exclusive scan of M ints in one block (M <= 1024*C). boffs gets M+1 entries.
// bcur gets a working copy of boffs[0..M-1].
extern "C" __global__ __launch_bounds__(1024) void k_scanb(const int* __restrict__ hist,
                                                           int* __restrict__ boffs,
                                                           int* __restrict__ bcur, int M) {
  __shared__ int sh[1024];
  int tid = threadIdx.x;
  int C = (M + 1023) / 1024;
  int base = tid * C;
  int s = 0;
  for (int k = 0; k < C; k++) {
    int idx = base + k;
    if (idx < M) s += hist[idx];
  }
  sh[tid] = s;
  __syncthreads();
  for (int d = 1; d < 1024; d <<= 1) {
    int t = (tid >= d) ? sh[tid - d] : 0;
    __syncthreads();
    sh[tid] += t;
    __syncthreads();
  }
  int run = sh[tid] - s;  // exclusive prefix of this chunk
  for (int k = 0; k < C; k++) {
    int idx = base + k;
    if (idx < M) {
      int v = hist[idx];
      boffs[idx] = run;
      bcur[idx] = run;
      run += v;
    }
  }
  if (tid == 1023) boffs[M] = run;  // total == E
}

// scatter edges into bucket regions as packed words: row | (local_col << 20)
extern "C" __global__ void k_bucket(const void* __restrict__ ei, int E, int* __restrict__ bcur,
                                    unsigned int* __restrict__ bked,
                                    const int* __restrict__ flag) {
  int e = blockIdx.x * blockDim.x + threadIdx.x;
  if (e >= E) return;
  int is64 = *flag;
  int r = load_idx(ei, is64, e);
  int c = load_idx(ei, is64, (long long)E + e);
  int idx = (c >> 6) * REPL + (blockIdx.x & (REPL - 1));
  int p = atomicAdd(&bcur[idx], 1);
  bked[p] = (unsigned int)r | ((unsigned int)(c & (BTGT - 1)) << 20);
}

// h1 = x @ W1 : [n,512]@[512,16], one row per thread (W loads wave-uniform)
extern "C" __global__ __launch_bounds__(256) void k_mm1(
    const float* __restrict__ x, const float* __restrict__ W1, float* __restrict__ h1, int n) {
  int r = blockIdx.x * 256 + threadIdx.x;
  if (r >= n) return;
  const float4* xr = (const float4*)(x + (long long)r * F_IN);
  float acc[HDIM];
#pragma unroll
  for (int j = 0; j < HDIM; j++) acc[j] = 0.f;
  for (int k4 = 0; k4 < F_IN / 4; k4++) {
    float4 xv = xr[k4];
    float xk[4] = {xv.x, xv.y, xv.z, xv.w};
#pragma unroll
    for (int kk = 0; kk < 4; kk++) {
      const float4* wr = (const float4*)(W1 + (long long)(4 * k4 + kk) * HDIM);
#pragma unroll
      for (int q = 0; q < HDIM / 4; q++) {
        float4 wv = wr[q];
        acc[4 * q + 0] = fmaf(xk[kk], wv.x, acc[4 * q + 0]);
        acc[4 * q + 1] = fmaf(xk[kk], wv.y, acc[4 * q + 1]);
        acc[4 * q + 2] = fmaf(xk[kk], wv.z, acc[4 * q + 2]);
        acc[4 * q + 3] = fmaf(xk[kk], wv.w, acc[4 * q + 3]);
      }
    }
  }
  float4* o = (float4*)(h1 + (long long)r * HDIM);
#pragma unroll
  for (int q = 0; q < HDIM / 4; q++)
    o[q] = make_float4(acc[4 * q], acc[4 * q + 1], acc[4 * q + 2], acc[4 * q + 3]);
}

// block = bucket of 64 consecutive targets; LDS accumulator 64x16 f32.
// 16 lanes per edge; message = dis[src]*h[src][j], ds_add_f32 into acc.
extern "C" __global__ __launch_bounds__(256) void k_agg(
    const float* __restrict__ hin, const unsigned int* __restrict__ bked,
    const int* __restrict__ boffs, const float* __restrict__ dis,
    const float* __restrict__ bias, int do_relu, float* __restrict__ hout, int n) {
  __shared__ float acc[BTGT * HDIM];
  int b = blockIdx.x;
  int t = threadIdx.x;
  int g = t >> 4;       // group 0..15
  int j = t & 15;       // feature
  for (int k = t; k < BTGT * HDIM; k += 256) acc[k] = 0.f;
  __syncthreads();
  int beg = boffs[b * REPL];
  int end = boffs[(b + 1) * REPL];
  for (int p = beg + g; p < end; p += 16) {
    unsigned int pk = bked[p];
    int s = (int)(pk & 0xFFFFFu);
    int lc = (int)(pk >> 20);
    float v = dis[s] * hin[(long long)s * HDIM + j];
    atomicAdd(&acc[lc * HDIM + j], v);
  }
  __syncthreads();
  for (int il = g; il < BTGT; il += 16) {
    int i = b * BTGT + il;
    if (i >= n) break;
    float di = dis[i];
    float v = di * acc[il * HDIM + j] + di * di * hin[(long long)i * HDIM + j];
    if (bias) v += bias[j];
    if (do_relu) v = fmaxf(v, 0.f);
    hout[(long long)i * HDIM + j] = v;
  }
}

// out = a2 @ W2 + b2 : [n,16]@[16,40], one row per thread
extern "C" __global__ __launch_bounds__(256) void k_mm2(
    const float* __restrict__ a2, const float* __restrict__ W2, const float* __restrict__ b2,
    float* __restrict__ out, int n) {
  int r = blockIdx.x * 256 + threadIdx.x;
  if (r >= n) return;
  float a[HDIM];
  const float4* ar = (const float4*)(a2 + (long long)r * HDIM);
#pragma unroll
  for (int q = 0; q < HDIM / 4; q++) {
    float4 v = ar[q];
    a[4 * q] = v.x; a[4 * q + 1] = v.y; a[4 * q + 2] = v.z; a[4 * q + 3] = v.w;
  }
  float acc[F_OUT];
#pragma unroll
  for (int jj = 0; jj < F_OUT; jj++) acc[jj] = b2[jj];
#pragma unroll
  for (int k = 0; k < HDIM; k++) {
    float ak = a[k];
    const float4* wr = (const float4*)(W2 + k * F_OUT);
#pragma unroll
    for (int q = 0; q < F_OUT / 4; q++) {
      float4 wv = wr[q];
      acc[4 * q + 0] = fmaf(ak, wv.x, acc[4 * q + 0]);
      acc[4 * q + 1] = fmaf(ak, wv.y, acc[4 * q + 1]);
      acc[4 * q + 2] = fmaf(ak, wv.z, acc[4 * q + 2]);
      acc[4 * q + 3] = fmaf(ak, wv.w, acc[4 * q + 3]);
    }
  }
  float4* o = (float4*)(out + (long long)r * F_OUT);
#pragma unroll
  for (int q = 0; q < F_OUT / 4; q++)
    o[q] = make_float4(acc[4 * q], acc[4 * q + 1], acc[4 * q + 2], acc[4 * q + 3]);
}

extern "C" void kernel_launch(void* const* d_in, const int* in_sizes, int n_in,
                              void* d_out, int out_size, void* d_ws, size_t ws_size,
                              hipStream_t stream) {
  const float* x = (const float*)d_in[0];
  const void* ei = d_in[1];
  const float* W1 = (const float*)d_in[2];
  const float* b1 = (const float*)d_in[3];
  const float* W2 = (const float*)d_in[4];
  const float* b2 = (const float*)d_in[5];
  float* out = (float*)d_out;

  const int n = in_sizes[0] / F_IN;  // 100000
  const int E = in_sizes[1] / 2;     // 3200000
  const int NB = (n + BTGT - 1) / BTGT;
  const int M = NB * REPL;

  char* w = (char*)d_ws;
  auto alloc = [&](size_t bytes) {
    char* p = w;
    w += (bytes + 255) & ~(size_t)255;
    return p;
  };
  int* cnt = (int*)alloc((size_t)n * 4);
  float* dis = (float*)alloc((size_t)n * 4);
  int* flag = (int*)alloc(4);
  int* hist = (int*)alloc((size_t)M * 4);
  int* boffs = (int*)alloc((size_t)(M + 1) * 4);
  int* bcur = (int*)alloc((size_t)M * 4);
  unsigned int* bked = (unsigned int*)alloc((size_t)E * 4);
  float* h1 = (float*)alloc((size_t)n * HDIM * 4);
  float* z = (float*)alloc((size_t)n * HDIM * 4);
  float* a2 = (float*)alloc((size_t)n * HDIM * 4);

  dim3 B(256);
  int nbi = ((n > M ? n : M) + 255) / 256;
  hipLaunchKernelGGL(k_init, dim3(nbi), B, 0, stream, cnt, n, hist, M, flag);
  int npairs = 4096;
  if (npairs > E) npairs = E;
  hipLaunchKernelGGL(k_detect, dim3((npairs + 255) / 256), B, 0, stream,
                     (const unsigned int*)ei, npairs, flag);
  hipLaunchKernelGGL(k_hist, dim3((E + 255) / 256), B, 0, stream, ei, E, cnt, hist, flag);
  hipLaunchKernelGGL(k_dis, dim3((n + 255) / 256), B, 0, stream, cnt, dis, n);
  hipLaunchKernelGGL(k_scanb, dim3(1), dim3(1024), 0, stream, hist, boffs, bcur, M);
  hipLaunchKernelGGL(k_bucket, dim3((E + 255) / 256), B, 0, stream, ei, E, bcur, bked, flag);
  hipLaunchKernelGGL(k_mm1, dim3((n + 255) / 256), B, 0, stream, x, W1, h1, n);
  hipLaunchKernelGGL(k_agg, dim3(NB), B, 0, stream, h1, bked, boffs, dis, b1, 1, z, n);
  hipLaunchKernelGGL(k_agg, dim3(NB), B, 0, stream, z, bked, boffs, dis,
                     (const float*)nullptr, 0, a2, n);
  hipLaunchKernelGGL(k_mm2, dim3((n + 255) / 256), B, 0, stream, a2, W2, b2, out, n);
}